// Round 5
// baseline (415.277 us; speedup 1.0000x reference)
//
#include <hip/hip_runtime.h>
#include <hip/hip_fp16.h>

typedef _Float16 f16x8 __attribute__((ext_vector_type(8)));  // 8 fp16 = 4 VGPRs (MFMA A/B)
typedef float fx4 __attribute__((ext_vector_type(4)));       // MFMA acc

#define AS_G(p) ((const __attribute__((address_space(1))) void*)(p))
#define AS_L(p) ((__attribute__((address_space(3))) void*)(p))

struct __align__(8) half4 { __half2 lo, hi; };
struct __align__(8) edge_t { int u; float w; };   // paired edge record: one 8B store/load

// fp16 two-term split for weights: hi = fp16(w), lo = fp16(w - hi)  (combined ~2^-23 rel)
__device__ inline void split2h(float a, __half& hi, __half& lo) {
    hi = __float2half(a);
    lo = __float2half(a - __half2float(hi));
}

// ===================== graph preprocessing =====================

// fused dispatch: blocks [0,degB) histogram degrees (4 edges/thread); blocks [degB,..) x -> fp16.
__global__ void k_degx(const int* __restrict__ dst, int E, int* __restrict__ deg, int degB,
                       const float* __restrict__ x, __half* __restrict__ xh, int nx) {
    if (blockIdx.x < (unsigned)degB) {
        int i = (blockIdx.x * 256 + threadIdx.x) * 4;
        if (i + 4 <= E) {
            int4 d4 = *(const int4*)&dst[i];
            atomicAdd(&deg[d4.x], 1);
            atomicAdd(&deg[d4.y], 1);
            atomicAdd(&deg[d4.z], 1);
            atomicAdd(&deg[d4.w], 1);
        } else {
            for (int j = i; j < E; ++j) atomicAdd(&deg[dst[j]], 1);
        }
    } else {
        int i = (blockIdx.x - degB) * 1024 + threadIdx.x * 4;
        if (i < nx) {
            float4 v = *(const float4*)&x[i];
            __half2 h0(__float2half(v.x), __float2half(v.y));
            __half2 h1(__float2half(v.z), __float2half(v.w));
            *(__half2*)&xh[i] = h0;
            *(__half2*)&xh[i + 2] = h1;
        }
    }
}

// fused dispatch: blocks [0,nb) deg-scan + dinv; blocks [nb,..) split/transpose weights to fp16 hi/lo.
__global__ void k_scan1w(const int* __restrict__ deg, int N, int nb,
                         int* __restrict__ part, int* __restrict__ bsum, float* __restrict__ dinv,
                         const float* __restrict__ W0, __half* __restrict__ h0, __half* __restrict__ l0,
                         const float* __restrict__ W1, __half* __restrict__ h1, __half* __restrict__ l1,
                         const float* __restrict__ W2, __half* __restrict__ h2, __half* __restrict__ l2,
                         int DIN, int DH) {
    __shared__ int s[256];
    if (blockIdx.x < (unsigned)nb) {
        int i = blockIdx.x * 256 + threadIdx.x;
        int v = (i < N) ? deg[i] : 0;
        if (i < N) dinv[i] = 1.0f / sqrtf((float)(v + 1));  // +1 self-loop
        s[threadIdx.x] = v;
        __syncthreads();
        for (int off = 1; off < 256; off <<= 1) {
            int t = (threadIdx.x >= off) ? s[threadIdx.x - off] : 0;
            __syncthreads();
            s[threadIdx.x] += t;
            __syncthreads();
        }
        if (i < N) part[i] = s[threadIdx.x] - v;
        if (threadIdx.x == 255) bsum[blockIdx.x] = s[255];
    } else {
        int i = (blockIdx.x - nb) * 256 + threadIdx.x;
        const int n0 = DIN * DH, n1 = DH * DH;
        const float* W; __half *hT, *lT; int K, li;
        if (i < n0) { W = W0; hT = h0; lT = l0; K = DIN; li = i; }
        else if (i < n0 + n1) { W = W1; hT = h1; lT = l1; K = DH; li = i - n0; }
        else if (i < n0 + 2 * n1) { W = W2; hT = h2; lT = l2; K = DH; li = i - n0 - n1; }
        else return;
        int k = li / DH, n = li - k * DH;
        __half h, l;
        split2h(W[li], h, l);
        hT[(size_t)n * K + k] = h;
        lT[(size_t)n * K + k] = l;
    }
}

// rowptr build; each block reduces the raw per-block sums itself (nb <= 256).
__global__ void k_scan3(const int* __restrict__ part, const int* __restrict__ bsum, int nb,
                        int N, int E, int* __restrict__ rowptr, int* __restrict__ cursor) {
    __shared__ int s[256];
    const int t = threadIdx.x;
    s[t] = (t < nb && t < (int)blockIdx.x) ? bsum[t] : 0;
    __syncthreads();
    for (int off = 128; off > 0; off >>= 1) {
        if (t < off) s[t] += s[t + off];
        __syncthreads();
    }
    const int base = s[0];
    int i = blockIdx.x * 256 + t;
    if (i < N) {
        int v = part[i] + base;
        rowptr[i] = v;
        cursor[i] = v;
    }
    if (i == 0) rowptr[N] = E;
}

__global__ void k_fill(const int* __restrict__ src, const int* __restrict__ dst, int E,
                       const float* __restrict__ dinv, int* __restrict__ cursor,
                       edge_t* __restrict__ edg) {
    int e = blockIdx.x * blockDim.x + threadIdx.x;
    if (e < E) {
        int s = src[e], d = dst[e];
        int p = atomicAdd(&cursor[d], 1);
        edge_t ed;
        ed.u = s;
        ed.w = dinv[s] * dinv[d];
        edg[p] = ed;
    }
}

// ===================== fp16 MFMA GEMM, 128 rows x 256 cols, 512 threads ==================
// r19: remove the per-iteration full vmcnt(0) drain that left the round-0 GEMM at ~10%
// MFMA util (all 391 blocks stall in lockstep on A-stage HBM latency, K too short for
// TLP to desync). Changes vs round-0 (math BIT-IDENTICAL, same tile/waves):
//  - B is NOT staged in LDS: per-lane 16B direct global loads of the natural fragment
//    B^T[rb][k0+quad*8]. A wave touches 16 fully-consumed 64B lines; B is L2-resident
//    (256KB); 2x redundancy across wrow pairs costs ~6us of L2 BW per GEMM.
//  - A double-buffered in LDS (8KB x 2), ONE global_load_lds per wave per iter, issued
//    AFTER the B loads so compiler-counted vmcnt lets MFMAs wait only on B (L2 ~200cy)
//    while the A-stage drains under the full compute phase + next barrier.
//  - ONE barrier per iteration (dbuf: both WAR and RAW protected by the top-of-iter
//    barrier, whose implicit per-wave vmcnt(0) drains the previous stage for all waves).
// Accumulation order per acc element unchanged (k0 asc, hi then lo) => bit-identical C.

__device__ __forceinline__ void gemm_core(
    const __half* __restrict__ Aop, const __half* __restrict__ BhiT, const __half* __restrict__ BloT,
    __half* smem, int Nrows, int K, int row0,
    int wid, int lane, int wrow, int wcol, int quad, int l16, fx4 (&acc)[4][4]) {
    // A stage: wave wid owns slot wid (16 rows x 32 k = 1KB), XOR swizzle folded into
    // the global source column (same scheme as round-0 => same LDS image per buffer).
    const int r = 16 * wid + (lane >> 2);
    const int s = lane & 3;
    const int q = (s - (r >> 1)) & 3;
    const __half* agp = Aop + (size_t)min(row0 + r, Nrows - 1) * K + q * 8;
    const int aslot = wid * 1024;        // byte offset inside an 8KB buffer

    // B direct-load bases (per nj, hi & lo): natural MFMA fragment addresses.
    const __half* bph[4];
    const __half* bpl[4];
#pragma unroll
    for (int t = 0; t < 4; ++t) {
        const int rb = wcol * 64 + t * 16 + l16;
        bph[t] = BhiT + (size_t)rb * K + quad * 8;
        bpl[t] = BloT + (size_t)rb * K + quad * 8;
    }

    int aidx[4];
#pragma unroll
    for (int t = 0; t < 4; ++t) {
        const int ra = wrow * 64 + t * 16 + l16;
        aidx[t] = ra * 32 + ((quad + (ra >> 1)) & 3) * 8;   // __half units within buffer
    }

    const int NI = K >> 5;
    // prologue: stage chunk 0 into buffer 0 (drained by the first barrier)
    __builtin_amdgcn_global_load_lds(AS_G(agp), AS_L((char*)smem + aslot), 16, 0, 0);

    for (int it = 0; it < NI; ++it) {
        __syncthreads();                  // drains prev stage (vmcnt0) for ALL waves; gates dbuf WAR/RAW
        const int k0 = it * 32;

        // B fragments first (L2 hits): MFMAs below wait only on these via counted vmcnt.
        f16x8 bh[4], bl[4];
#pragma unroll
        for (int nj = 0; nj < 4; ++nj) {
            bh[nj] = *(const f16x8*)(bph[nj] + k0);
            bl[nj] = *(const f16x8*)(bpl[nj] + k0);
        }

        // A-stage for next iter, issued after B: stays in flight through this iter's
        // compute and is drained by the next barrier.
        if (it + 1 < NI)
            __builtin_amdgcn_global_load_lds(AS_G(agp + (it + 1) * 32),
                AS_L((char*)smem + (((it + 1) & 1) << 13) + aslot), 16, 0, 0);

        const __half* sA = (const __half*)((const char*)smem + ((it & 1) << 13));
        f16x8 a[4];
#pragma unroll
        for (int mi = 0; mi < 4; ++mi) a[mi] = *(const f16x8*)&sA[aidx[mi]];

#pragma unroll
        for (int nj = 0; nj < 4; ++nj)
#pragma unroll
            for (int mi = 0; mi < 4; ++mi) {
                acc[mi][nj] = __builtin_amdgcn_mfma_f32_16x16x32_f16(a[mi], bh[nj], acc[mi][nj], 0, 0, 0);
                acc[mi][nj] = __builtin_amdgcn_mfma_f32_16x16x32_f16(a[mi], bl[nj], acc[mi][nj], 0, 0, 0);
            }
    }
}

__global__ __launch_bounds__(512) void k_gemm_mfma(
    const __half* __restrict__ Aop, const __half* __restrict__ BhiT, const __half* __restrict__ BloT,
    const float* __restrict__ bias, __half* __restrict__ C, int Nrows, int K) {
    __shared__ __align__(16) __half smem[8192];    // 16 KB: A dbuf only
    const int tid = threadIdx.x;
    const int wid = tid >> 6, lane = tid & 63;
    const int row0 = blockIdx.x * 128;
    const int wrow = wid & 1, wcol = wid >> 1;     // 2 x 4 wave grid
    const int quad = lane >> 4, l16 = lane & 15;

    fx4 acc[4][4] = {};
    gemm_core(Aop, BhiT, BloT, smem, Nrows, K, row0, wid, lane, wrow, wcol, quad, l16, acc);

    // C/D layout: col = lane&15, row = quad*4 + reg  [m89-verified, dtype-independent]
#pragma unroll
    for (int mi = 0; mi < 4; ++mi) {
        const int rbase = row0 + wrow * 64 + mi * 16 + quad * 4;
#pragma unroll
        for (int nj = 0; nj < 4; ++nj) {
            const int c = wcol * 64 + nj * 16 + l16;
            const float bc = bias[c];
#pragma unroll
            for (int reg = 0; reg < 4; ++reg) {
                int r = rbase + reg;
                if (r < Nrows) C[(size_t)r * 256 + c] = __float2half(fmaxf(acc[mi][nj][reg] + bc, 0.f));
            }
        }
    }
}

// Layer-2 variant: relu(acc+bias) pooled per-graph into gsum[64][256]
__global__ __launch_bounds__(512) void k_gemm_pool(
    const __half* __restrict__ Aop, const __half* __restrict__ BhiT, const __half* __restrict__ BloT,
    const float* __restrict__ bias, const int* __restrict__ batch,
    float* __restrict__ gsum, int Nrows, int K) {
    __shared__ __align__(16) __half smem[8192];
    const int tid = threadIdx.x;
    const int wid = tid >> 6, lane = tid & 63;
    const int row0 = blockIdx.x * 128;
    const int wrow = wid & 1, wcol = wid >> 1;
    const int quad = lane >> 4, l16 = lane & 15;

    fx4 acc[4][4] = {};
    gemm_core(Aop, BhiT, BloT, smem, Nrows, K, row0, wid, lane, wrow, wcol, quad, l16, acc);

    int bg[4][4];
#pragma unroll
    for (int mi = 0; mi < 4; ++mi)
#pragma unroll
        for (int reg = 0; reg < 4; ++reg) {
            int r = row0 + wrow * 64 + mi * 16 + quad * 4 + reg;
            bg[mi][reg] = (r < Nrows) ? batch[r] : -1;
        }
    const int gfirst = batch[row0 < Nrows ? row0 : (Nrows - 1)];
    const int glast  = batch[min(row0 + 127, Nrows - 1)];

#pragma unroll
    for (int nj = 0; nj < 4; ++nj) {
        const int c = wcol * 64 + nj * 16 + l16;
        const float bc = bias[c];
        for (int g = gfirst; g <= glast; ++g) {
            float s = 0.f;
#pragma unroll
            for (int mi = 0; mi < 4; ++mi)
#pragma unroll
                for (int reg = 0; reg < 4; ++reg)
                    if (bg[mi][reg] == g) s += fmaxf(acc[mi][nj][reg] + bc, 0.f);
            s += __shfl_xor(s, 16);
            s += __shfl_xor(s, 32);
            if (quad == 0) atomicAdd(&gsum[g * 256 + c], s);
        }
    }
}

// ===================== aggregation (fp16 gather, fp32 accumulate, fp16 out) =============
// WAVE-PER-NODE, r14 inner loop + fixed grid — proven best. r15 (predication), r16
// (persistent), r17 (gemm overlap) all regressed or neutral: throughput pinned by
// per-CU outstanding-request capacity at ~3.4 TB/s for this random-512B pattern,
// insensitive to occupancy/MLP levers. Do not touch.

__global__ __launch_bounds__(256) void k_agg256(const __half* __restrict__ H, const int* __restrict__ rowptr,
                                                const edge_t* __restrict__ edg,
                                                const float* __restrict__ dinv,
                                                __half* __restrict__ outA, int N) {
    const int wave = threadIdx.x >> 6, lane = threadIdx.x & 63;
    const int v = blockIdx.x * 4 + wave;
    if (v >= N) return;

    const float di = dinv[v];
    const float selfn = di * di;
    half4 hv = ((const half4*)&H[(size_t)v * 256])[lane];
    float2 s0 = __half22float2(hv.lo), s1 = __half22float2(hv.hi);
    float ax = selfn * s0.x, ay = selfn * s0.y, az = selfn * s1.x, aw = selfn * s1.y;

    int e = rowptr[v];
    const int end = rowptr[v + 1];
    for (; e + 8 <= end; e += 8) {
        edge_t ed[8]; half4 g[8];
#pragma unroll
        for (int j = 0; j < 8; ++j) ed[j] = edg[e + j];
#pragma unroll
        for (int j = 0; j < 8; ++j) g[j] = ((const half4*)&H[(size_t)ed[j].u * 256])[lane];
#pragma unroll
        for (int j = 0; j < 8; ++j) {
            float2 f0 = __half22float2(g[j].lo), f1 = __half22float2(g[j].hi);
            ax += ed[j].w * f0.x; ay += ed[j].w * f0.y; az += ed[j].w * f1.x; aw += ed[j].w * f1.y;
        }
    }
    for (; e < end; ++e) {
        edge_t ed = edg[e];
        half4 g = ((const half4*)&H[(size_t)ed.u * 256])[lane];
        float2 f0 = __half22float2(g.lo), f1 = __half22float2(g.hi);
        ax += ed.w * f0.x; ay += ed.w * f0.y; az += ed.w * f1.x; aw += ed.w * f1.y;
    }

    half4 o;
    o.lo = __floats2half2_rn(ax, ay);
    o.hi = __floats2half2_rn(az, aw);
    ((half4*)outA)[(size_t)v * 64 + lane] = o;
}

__global__ __launch_bounds__(256) void k_agg128(const __half* __restrict__ X, const int* __restrict__ rowptr,
                                                const edge_t* __restrict__ edg,
                                                const float* __restrict__ dinv,
                                                __half* __restrict__ outA, int N) {
    const int half = threadIdx.x >> 5, sub = threadIdx.x & 31;
    const int v = blockIdx.x * 8 + half;
    if (v >= N) return;

    const float di = dinv[v];
    const float selfn = di * di;
    half4 hv = ((const half4*)&X[(size_t)v * 128])[sub];
    float2 s0 = __half22float2(hv.lo), s1 = __half22float2(hv.hi);
    float ax = selfn * s0.x, ay = selfn * s0.y, az = selfn * s1.x, aw = selfn * s1.y;

    int e = rowptr[v];
    const int end = rowptr[v + 1];
    for (; e + 4 <= end; e += 4) {
        edge_t ed[4]; half4 g[4];
#pragma unroll
        for (int j = 0; j < 4; ++j) ed[j] = edg[e + j];
#pragma unroll
        for (int j = 0; j < 4; ++j) g[j] = ((const half4*)&X[(size_t)ed[j].u * 128])[sub];
#pragma unroll
        for (int j = 0; j < 4; ++j) {
            float2 f0 = __half22float2(g[j].lo), f1 = __half22float2(g[j].hi);
            ax += ed[j].w * f0.x; ay += ed[j].w * f0.y; az += ed[j].w * f1.x; aw += ed[j].w * f1.y;
        }
    }
    for (; e < end; ++e) {
        edge_t ed = edg[e];
        half4 g = ((const half4*)&X[(size_t)ed.u * 128])[sub];
        float2 f0 = __half22float2(g.lo), f1 = __half22float2(g.hi);
        ax += ed.w * f0.x; ay += ed.w * f0.y; az += ed.w * f1.x; aw += ed.w * f1.y;
    }

    half4 o;
    o.lo = __floats2half2_rn(ax, ay);
    o.hi = __floats2half2_rn(az, aw);
    ((half4*)outA)[(size_t)v * 32 + sub] = o;
}

// ===================== fused mean-pool finalize + classifier head =====================

__global__ __launch_bounds__(256) void k_poolcls(const float* __restrict__ gsum, const int* __restrict__ batch,
                                                 int N,
                                                 const float* __restrict__ Wc1, const float* __restrict__ bc1,
                                                 const float* __restrict__ Wc2, const float* __restrict__ bc2,
                                                 float* __restrict__ out) {
    __shared__ float sg[256], sh[256];
    __shared__ int bounds[2];
    const int b = blockIdx.x, t = threadIdx.x;
    if (t < 2) {
        int target = b + t;
        int lo = 0, hi = N;
        while (lo < hi) {
            int mid = (lo + hi) >> 1;
            if (batch[mid] < target) lo = mid + 1; else hi = mid;
        }
        bounds[t] = lo;
    }
    __syncthreads();
    const float c = (float)(bounds[1] - bounds[0]);
    sg[t] = gsum[b * 256 + t] / fmaxf(c, 1.0f);
    __syncthreads();
    float acc = bc1[t];
    for (int k = 0; k < 256; ++k) acc += sg[k] * Wc1[k * 256 + t];
    sh[t] = fmaxf(acc, 0.f);
    __syncthreads();
    if (t < 5) {
        float o = bc2[t];
        for (int k = 0; k < 256; ++k) o += sh[k] * Wc2[k * 5 + t];
        out[b * 5 + t] = o;
    }
}

// ===================== launch =====================

extern "C" void kernel_launch(void* const* d_in, const int* in_sizes, int n_in,
                              void* d_out, int out_size, void* d_ws, size_t ws_size,
                              hipStream_t stream) {
    const float* x    = (const float*)d_in[0];
    const int*   eidx = (const int*)d_in[1];
    const int*   batch= (const int*)d_in[2];
    const float* W0 = (const float*)d_in[3];  const float* b0 = (const float*)d_in[4];
    const float* W1 = (const float*)d_in[5];  const float* b1 = (const float*)d_in[6];
    const float* W2 = (const float*)d_in[7];  const float* b2 = (const float*)d_in[8];
    const float* Wc1= (const float*)d_in[9];  const float* bc1= (const float*)d_in[10];
    const float* Wc2= (const float*)d_in[11]; const float* bc2= (const float*)d_in[12];
    float* out = (float*)d_out;

    const int N   = in_sizes[2];       // 50000
    const int E   = in_sizes[1] / 2;   // 500000
    const int DIN = in_sizes[0] / N;   // 128
    const int DH  = in_sizes[4];       // 256
    const int* src = eidx;
    const int* dst = eidx + E;

    char* p = (char*)d_ws;
    auto alloc = [&](size_t bytes) {
        char* r = p;
        p += (bytes + 255) & ~(size_t)255;
        return (void*)r;
    };
    __half* hbuf = (__half*)alloc((size_t)N * DH * 2);   // gemm out (fp16), agg gather in
    __half* ha   = (__half*)alloc((size_t)N * DH * 2);   // agg out / gemm A in (fp16)
    __half* xh   = (__half*)alloc((size_t)N * DIN * 2);  // x in fp16
    __half* w0hi = (__half*)alloc((size_t)DH * DIN * 2);
    __half* w0lo = (__half*)alloc((size_t)DH * DIN * 2);
    __half* w1hi = (__half*)alloc((size_t)DH * DH * 2);
    __half* w1lo = (__half*)alloc((size_t)DH * DH * 2);
    __half* w2hi = (__half*)alloc((size_t)DH * DH * 2);
    __half* w2lo = (__half*)alloc((size_t)DH * DH * 2);
    int*   deg   = (int*)alloc((size_t)N * 4);
    float* gsum  = (float*)alloc(64 * (size_t)DH * 4);   // adjacent to deg: one memset covers both
    float* dinv  = (float*)alloc((size_t)N * 4);
    int*   part  = (int*)alloc((size_t)N * 4);
    int*   bsum  = (int*)alloc(256 * 4);
    int*   rowptr= (int*)alloc((size_t)(N + 1) * 4);
    int*   cursor= (int*)alloc((size_t)N * 4);
    edge_t* edg  = (edge_t*)alloc((size_t)E * 8);

    hipMemsetAsync(deg, 0, (size_t)((char*)gsum - (char*)deg) + 64 * (size_t)DH * 4, stream);

    const int nb = (N + 255) / 256;
    const int wtot = DIN * DH + 2 * DH * DH;
    const int wb = (wtot + 255) / 256;
    const int degB = (E + 1023) / 1024;
    const int nx = N * DIN;
    const int xb = (nx + 1023) / 1024;

    k_degx  <<<degB + xb, 256, 0, stream>>>(dst, E, deg, degB, x, xh, nx);
    k_scan1w<<<nb + wb, 256, 0, stream>>>(deg, N, nb, part, bsum, dinv,
                                          W0, w0hi, w0lo, W1, w1hi, w1lo, W2, w2hi, w2lo, DIN, DH);
    k_scan3 <<<nb, 256, 0, stream>>>(part, bsum, nb, N, E, rowptr, cursor);
    k_fill  <<<(E + 255) / 256, 256, 0, stream>>>(src, dst, E, dinv, cursor, edg);

    const int gemmBlocks = (N + 127) / 128;

    // layer 0: agg(x fp16) -> fp16 A -> gemm(relu(.W0+b0)) -> fp16 H
    k_agg128<<<(N + 7) / 8, 256, 0, stream>>>(xh, rowptr, edg, dinv, ha, N);
    k_gemm_mfma<<<gemmBlocks, 512, 0, stream>>>(ha, w0hi, w0lo, b0, hbuf, N, DIN);
    // layer 1
    k_agg256<<<(N + 3) / 4, 256, 0, stream>>>(hbuf, rowptr, edg, dinv, ha, N);
    k_gemm_mfma<<<gemmBlocks, 512, 0, stream>>>(ha, w1hi, w1lo, b1, hbuf, N, DH);
    // layer 2 (fused pooling epilogue)
    k_agg256<<<(N + 3) / 4, 256, 0, stream>>>(hbuf, rowptr, edg, dinv, ha, N);
    k_gemm_pool<<<gemmBlocks, 512, 0, stream>>>(ha, w2hi, w2lo, b2, batch, gsum, N, DH);

    k_poolcls<<<64, 256, 0, stream>>>(gsum, batch, N, Wc1, bc1, Wc2, bc2, out);
}

// Round 6
// 346.928 us; speedup vs baseline: 1.1970x; 1.1970x over previous
//
#include <hip/hip_runtime.h>
#include <hip/hip_fp16.h>

typedef _Float16 f16x8 __attribute__((ext_vector_type(8)));  // 8 fp16 = 4 VGPRs (MFMA A/B)
typedef float fx4 __attribute__((ext_vector_type(4)));       // MFMA acc

#define AS_G(p) ((const __attribute__((address_space(1))) void*)(p))
#define AS_L(p) ((__attribute__((address_space(3))) void*)(p))

struct __align__(8) half4 { __half2 lo, hi; };
struct __align__(8) edge_t { int u; float w; };   // paired edge record: one 8B store/load

// fp16 two-term split for weights: hi = fp16(w), lo = fp16(w - hi)  (combined ~2^-23 rel)
__device__ inline void split2h(float a, __half& hi, __half& lo) {
    hi = __float2half(a);
    lo = __float2half(a - __half2float(hi));
}

// ===================== graph preprocessing =====================

// fused dispatch: blocks [0,degB) histogram degrees (4 edges/thread); blocks [degB,..) x -> fp16.
__global__ void k_degx(const int* __restrict__ dst, int E, int* __restrict__ deg, int degB,
                       const float* __restrict__ x, __half* __restrict__ xh, int nx) {
    if (blockIdx.x < (unsigned)degB) {
        int i = (blockIdx.x * 256 + threadIdx.x) * 4;
        if (i + 4 <= E) {
            int4 d4 = *(const int4*)&dst[i];
            atomicAdd(&deg[d4.x], 1);
            atomicAdd(&deg[d4.y], 1);
            atomicAdd(&deg[d4.z], 1);
            atomicAdd(&deg[d4.w], 1);
        } else {
            for (int j = i; j < E; ++j) atomicAdd(&deg[dst[j]], 1);
        }
    } else {
        int i = (blockIdx.x - degB) * 1024 + threadIdx.x * 4;
        if (i < nx) {
            float4 v = *(const float4*)&x[i];
            __half2 h0(__float2half(v.x), __float2half(v.y));
            __half2 h1(__float2half(v.z), __float2half(v.w));
            *(__half2*)&xh[i] = h0;
            *(__half2*)&xh[i + 2] = h1;
        }
    }
}

// fused dispatch: blocks [0,nb) deg-scan + dinv; blocks [nb,..) split/transpose weights to fp16 hi/lo.
__global__ void k_scan1w(const int* __restrict__ deg, int N, int nb,
                         int* __restrict__ part, int* __restrict__ bsum, float* __restrict__ dinv,
                         const float* __restrict__ W0, __half* __restrict__ h0, __half* __restrict__ l0,
                         const float* __restrict__ W1, __half* __restrict__ h1, __half* __restrict__ l1,
                         const float* __restrict__ W2, __half* __restrict__ h2, __half* __restrict__ l2,
                         int DIN, int DH) {
    __shared__ int s[256];
    if (blockIdx.x < (unsigned)nb) {
        int i = blockIdx.x * 256 + threadIdx.x;
        int v = (i < N) ? deg[i] : 0;
        if (i < N) dinv[i] = 1.0f / sqrtf((float)(v + 1));  // +1 self-loop
        s[threadIdx.x] = v;
        __syncthreads();
        for (int off = 1; off < 256; off <<= 1) {
            int t = (threadIdx.x >= off) ? s[threadIdx.x - off] : 0;
            __syncthreads();
            s[threadIdx.x] += t;
            __syncthreads();
        }
        if (i < N) part[i] = s[threadIdx.x] - v;
        if (threadIdx.x == 255) bsum[blockIdx.x] = s[255];
    } else {
        int i = (blockIdx.x - nb) * 256 + threadIdx.x;
        const int n0 = DIN * DH, n1 = DH * DH;
        const float* W; __half *hT, *lT; int K, li;
        if (i < n0) { W = W0; hT = h0; lT = l0; K = DIN; li = i; }
        else if (i < n0 + n1) { W = W1; hT = h1; lT = l1; K = DH; li = i - n0; }
        else if (i < n0 + 2 * n1) { W = W2; hT = h2; lT = l2; K = DH; li = i - n0 - n1; }
        else return;
        int k = li / DH, n = li - k * DH;
        __half h, l;
        split2h(W[li], h, l);
        hT[(size_t)n * K + k] = h;
        lT[(size_t)n * K + k] = l;
    }
}

// rowptr build; each block reduces the raw per-block sums itself (nb <= 256).
__global__ void k_scan3(const int* __restrict__ part, const int* __restrict__ bsum, int nb,
                        int N, int E, int* __restrict__ rowptr, int* __restrict__ cursor) {
    __shared__ int s[256];
    const int t = threadIdx.x;
    s[t] = (t < nb && t < (int)blockIdx.x) ? bsum[t] : 0;
    __syncthreads();
    for (int off = 128; off > 0; off >>= 1) {
        if (t < off) s[t] += s[t + off];
        __syncthreads();
    }
    const int base = s[0];
    int i = blockIdx.x * 256 + t;
    if (i < N) {
        int v = part[i] + base;
        rowptr[i] = v;
        cursor[i] = v;
    }
    if (i == 0) rowptr[N] = E;
}

__global__ void k_fill(const int* __restrict__ src, const int* __restrict__ dst, int E,
                       const float* __restrict__ dinv, int* __restrict__ cursor,
                       edge_t* __restrict__ edg) {
    int e = blockIdx.x * blockDim.x + threadIdx.x;
    if (e < E) {
        int s = src[e], d = dst[e];
        int p = atomicAdd(&cursor[d], 1);
        edge_t ed;
        ed.u = s;
        ed.w = dinv[s] * dinv[d];
        edg[p] = ed;
    }
}

// ===================== fp16 MFMA GEMM, BN=256 (full output width per block) =============
// Block = 128 rows x 256 cols, 512 threads (8 waves, 2 row-groups x 4 col-groups of
// 64x64 wave tiles). Per-wave math identical to the proven r14 kernel => bit-identical.
// r20: T3 "minimum 2-phase" K-loop — LDS double-buffered (40KB x 2 = 80KB, still >= the
// 1.53 blocks/CU grid), stage for chunk t+1 issued BEFORE computing chunk t, ONE barrier
// per iter (its implicit vmcnt(0) drains the stage that had the whole compute phase to
// fly). Round-0's loop drained the just-issued stage at every iter (zero overlap, ~8%
// MfmaUtil measured r19-adjacent). Staging addresses / LDS image per buffer / fragment
// indices / accumulation order unchanged => bit-identical C. [r13 notes dbuf "neutral"
// as the downside bound; r18 (64-row tile) and r19 (B-direct, uncoalesced) both hurt.]

__device__ __forceinline__ void gemm_core(
    const __half* __restrict__ Aop, const __half* __restrict__ BhiT, const __half* __restrict__ BloT,
    __half* smem, int Nrows, int K, int row0,
    int wid, int lane, int wrow, int wcol, int quad, int l16, fx4 (&acc)[4][4]) {
    // 40 1KB stage-slots per buffer: A 0..7 (128 rows), Bhi 8..23 (256 rows), Blo 24..39.
    const __half* gp[5];
    int ldsoff[5];
#pragma unroll
    for (int j = 0; j < 5; ++j) {
        int L = wid * 5 + j;
        int arr, slot;
        if (L < 8) { arr = 0; slot = L; }
        else if (L < 24) { arr = 1; slot = L - 8; }
        else { arr = 2; slot = L - 24; }
        int r = 16 * slot + (lane >> 2);
        int s = lane & 3;
        int q = (s - (r >> 1)) & 3;              // XOR swizzle folded into global addr
        const __half* garr = (arr == 0) ? Aop : (arr == 1) ? BhiT : BloT;
        int grow = (arr == 0) ? min(row0 + r, Nrows - 1) : r;
        gp[j] = garr + (size_t)grow * K + q * 8;
        ldsoff[j] = ((arr == 0) ? 0 : (arr == 1) ? 8192 : 24576) + slot * 1024;
    }

    int aidx[4], bidx[4];
#pragma unroll
    for (int t = 0; t < 4; ++t) {
        int ra = wrow * 64 + t * 16 + l16;
        aidx[t] = ra * 32 + ((quad + (ra >> 1)) & 3) * 8;
        int rb = wcol * 64 + t * 16 + l16;       // wcol in [0,4): covers 256 B-rows
        bidx[t] = rb * 32 + ((quad + (rb >> 1)) & 3) * 8;
    }

    const int NI = K >> 5;
    // prologue: stage chunk 0 into buffer 0; the first barrier drains it for all waves.
#pragma unroll
    for (int j = 0; j < 5; ++j)
        __builtin_amdgcn_global_load_lds(AS_G(gp[j]), AS_L((char*)smem + ldsoff[j]), 16, 0, 0);

    for (int it = 0; it < NI; ++it) {
        __syncthreads();   // drains previous stage (implicit vmcnt0) for ALL waves; gates dbuf WAR/RAW

        // stage chunk it+1 into the other buffer BEFORE computing chunk it:
        // it flies under the whole ds_read+MFMA phase and is drained by the next barrier.
        if (it + 1 < NI) {
            const int koff = (it + 1) * 32;
            const int boff = ((it + 1) & 1) * 40960;
#pragma unroll
            for (int j = 0; j < 5; ++j)
                __builtin_amdgcn_global_load_lds(AS_G(gp[j] + koff),
                    AS_L((char*)smem + boff + ldsoff[j]), 16, 0, 0);
        }

        const __half* buf  = smem + (it & 1) * 20480;   // 40KB buffer select (in halfs)
        const __half* sA   = buf;                       // 128 x 32
        const __half* sBhi = buf + 4096;                // 256 x 32
        const __half* sBlo = buf + 12288;               // 256 x 32

        f16x8 a[4];
#pragma unroll
        for (int mi = 0; mi < 4; ++mi) a[mi] = *(const f16x8*)&sA[aidx[mi]];
#pragma unroll
        for (int nj = 0; nj < 4; ++nj) {
            f16x8 bh = *(const f16x8*)&sBhi[bidx[nj]];
            f16x8 bl = *(const f16x8*)&sBlo[bidx[nj]];
#pragma unroll
            for (int mi = 0; mi < 4; ++mi) {
                acc[mi][nj] = __builtin_amdgcn_mfma_f32_16x16x32_f16(a[mi], bh, acc[mi][nj], 0, 0, 0);
                acc[mi][nj] = __builtin_amdgcn_mfma_f32_16x16x32_f16(a[mi], bl, acc[mi][nj], 0, 0, 0);
            }
        }
    }
}

__global__ __launch_bounds__(512) void k_gemm_mfma(
    const __half* __restrict__ Aop, const __half* __restrict__ BhiT, const __half* __restrict__ BloT,
    const float* __restrict__ bias, __half* __restrict__ C, int Nrows, int K) {
    __shared__ __align__(16) __half smem[40960];   // 80 KB: 2 x 40KB stage buffers
    const int tid = threadIdx.x;
    const int wid = tid >> 6, lane = tid & 63;
    const int row0 = blockIdx.x * 128;
    const int wrow = wid & 1, wcol = wid >> 1;     // 2 x 4 wave grid
    const int quad = lane >> 4, l16 = lane & 15;

    fx4 acc[4][4] = {};
    gemm_core(Aop, BhiT, BloT, smem, Nrows, K, row0, wid, lane, wrow, wcol, quad, l16, acc);

    // C/D layout: col = lane&15, row = quad*4 + reg  [m89-verified, dtype-independent]
#pragma unroll
    for (int mi = 0; mi < 4; ++mi) {
        const int rbase = row0 + wrow * 64 + mi * 16 + quad * 4;
#pragma unroll
        for (int nj = 0; nj < 4; ++nj) {
            const int c = wcol * 64 + nj * 16 + l16;
            const float bc = bias[c];
#pragma unroll
            for (int reg = 0; reg < 4; ++reg) {
                int r = rbase + reg;
                if (r < Nrows) C[(size_t)r * 256 + c] = __float2half(fmaxf(acc[mi][nj][reg] + bc, 0.f));
            }
        }
    }
}

// Layer-2 variant: relu(acc+bias) pooled per-graph into gsum[64][256]
__global__ __launch_bounds__(512) void k_gemm_pool(
    const __half* __restrict__ Aop, const __half* __restrict__ BhiT, const __half* __restrict__ BloT,
    const float* __restrict__ bias, const int* __restrict__ batch,
    float* __restrict__ gsum, int Nrows, int K) {
    __shared__ __align__(16) __half smem[40960];
    const int tid = threadIdx.x;
    const int wid = tid >> 6, lane = tid & 63;
    const int row0 = blockIdx.x * 128;
    const int wrow = wid & 1, wcol = wid >> 1;
    const int quad = lane >> 4, l16 = lane & 15;

    fx4 acc[4][4] = {};
    gemm_core(Aop, BhiT, BloT, smem, Nrows, K, row0, wid, lane, wrow, wcol, quad, l16, acc);

    int bg[4][4];
#pragma unroll
    for (int mi = 0; mi < 4; ++mi)
#pragma unroll
        for (int reg = 0; reg < 4; ++reg) {
            int r = row0 + wrow * 64 + mi * 16 + quad * 4 + reg;
            bg[mi][reg] = (r < Nrows) ? batch[r] : -1;
        }
    const int gfirst = batch[row0 < Nrows ? row0 : (Nrows - 1)];
    const int glast  = batch[min(row0 + 127, Nrows - 1)];

#pragma unroll
    for (int nj = 0; nj < 4; ++nj) {
        const int c = wcol * 64 + nj * 16 + l16;
        const float bc = bias[c];
        for (int g = gfirst; g <= glast; ++g) {
            float s = 0.f;
#pragma unroll
            for (int mi = 0; mi < 4; ++mi)
#pragma unroll
                for (int reg = 0; reg < 4; ++reg)
                    if (bg[mi][reg] == g) s += fmaxf(acc[mi][nj][reg] + bc, 0.f);
            s += __shfl_xor(s, 16);
            s += __shfl_xor(s, 32);
            if (quad == 0) atomicAdd(&gsum[g * 256 + c], s);
        }
    }
}

// ===================== aggregation (fp16 gather, fp32 accumulate, fp16 out) =============
// WAVE-PER-NODE, r14 inner loop + fixed grid — proven best (339.5us round-0). r15
// (predication), r16 (persistent), r17 (gemm overlap) all regressed or neutral:
// throughput pinned by per-CU outstanding-request capacity at ~3.4 TB/s for this
// random-512B pattern, insensitive to occupancy/MLP levers. Do not touch.

__global__ __launch_bounds__(256) void k_agg256(const __half* __restrict__ H, const int* __restrict__ rowptr,
                                                const edge_t* __restrict__ edg,
                                                const float* __restrict__ dinv,
                                                __half* __restrict__ outA, int N) {
    const int wave = threadIdx.x >> 6, lane = threadIdx.x & 63;
    const int v = blockIdx.x * 4 + wave;
    if (v >= N) return;

    const float di = dinv[v];
    const float selfn = di * di;
    half4 hv = ((const half4*)&H[(size_t)v * 256])[lane];
    float2 s0 = __half22float2(hv.lo), s1 = __half22float2(hv.hi);
    float ax = selfn * s0.x, ay = selfn * s0.y, az = selfn * s1.x, aw = selfn * s1.y;

    int e = rowptr[v];
    const int end = rowptr[v + 1];
    for (; e + 8 <= end; e += 8) {
        edge_t ed[8]; half4 g[8];
#pragma unroll
        for (int j = 0; j < 8; ++j) ed[j] = edg[e + j];
#pragma unroll
        for (int j = 0; j < 8; ++j) g[j] = ((const half4*)&H[(size_t)ed[j].u * 256])[lane];
#pragma unroll
        for (int j = 0; j < 8; ++j) {
            float2 f0 = __half22float2(g[j].lo), f1 = __half22float2(g[j].hi);
            ax += ed[j].w * f0.x; ay += ed[j].w * f0.y; az += ed[j].w * f1.x; aw += ed[j].w * f1.y;
        }
    }
    for (; e < end; ++e) {
        edge_t ed = edg[e];
        half4 g = ((const half4*)&H[(size_t)ed.u * 256])[lane];
        float2 f0 = __half22float2(g.lo), f1 = __half22float2(g.hi);
        ax += ed.w * f0.x; ay += ed.w * f0.y; az += ed.w * f1.x; aw += ed.w * f1.y;
    }

    half4 o;
    o.lo = __floats2half2_rn(ax, ay);
    o.hi = __floats2half2_rn(az, aw);
    ((half4*)outA)[(size_t)v * 64 + lane] = o;
}

__global__ __launch_bounds__(256) void k_agg128(const __half* __restrict__ X, const int* __restrict__ rowptr,
                                                const edge_t* __restrict__ edg,
                                                const float* __restrict__ dinv,
                                                __half* __restrict__ outA, int N) {
    const int half = threadIdx.x >> 5, sub = threadIdx.x & 31;
    const int v = blockIdx.x * 8 + half;
    if (v >= N) return;

    const float di = dinv[v];
    const float selfn = di * di;
    half4 hv = ((const half4*)&X[(size_t)v * 128])[sub];
    float2 s0 = __half22float2(hv.lo), s1 = __half22float2(hv.hi);
    float ax = selfn * s0.x, ay = selfn * s0.y, az = selfn * s1.x, aw = selfn * s1.y;

    int e = rowptr[v];
    const int end = rowptr[v + 1];
    for (; e + 4 <= end; e += 4) {
        edge_t ed[4]; half4 g[4];
#pragma unroll
        for (int j = 0; j < 4; ++j) ed[j] = edg[e + j];
#pragma unroll
        for (int j = 0; j < 4; ++j) g[j] = ((const half4*)&X[(size_t)ed[j].u * 128])[sub];
#pragma unroll
        for (int j = 0; j < 4; ++j) {
            float2 f0 = __half22float2(g[j].lo), f1 = __half22float2(g[j].hi);
            ax += ed[j].w * f0.x; ay += ed[j].w * f0.y; az += ed[j].w * f1.x; aw += ed[j].w * f1.y;
        }
    }
    for (; e < end; ++e) {
        edge_t ed = edg[e];
        half4 g = ((const half4*)&X[(size_t)ed.u * 128])[sub];
        float2 f0 = __half22float2(g.lo), f1 = __half22float2(g.hi);
        ax += ed.w * f0.x; ay += ed.w * f0.y; az += ed.w * f1.x; aw += ed.w * f1.y;
    }

    half4 o;
    o.lo = __floats2half2_rn(ax, ay);
    o.hi = __floats2half2_rn(az, aw);
    ((half4*)outA)[(size_t)v * 32 + sub] = o;
}

// ===================== fused mean-pool finalize + classifier head =====================

__global__ __launch_bounds__(256) void k_poolcls(const float* __restrict__ gsum, const int* __restrict__ batch,
                                                 int N,
                                                 const float* __restrict__ Wc1, const float* __restrict__ bc1,
                                                 const float* __restrict__ Wc2, const float* __restrict__ bc2,
                                                 float* __restrict__ out) {
    __shared__ float sg[256], sh[256];
    __shared__ int bounds[2];
    const int b = blockIdx.x, t = threadIdx.x;
    if (t < 2) {
        int target = b + t;
        int lo = 0, hi = N;
        while (lo < hi) {
            int mid = (lo + hi) >> 1;
            if (batch[mid] < target) lo = mid + 1; else hi = mid;
        }
        bounds[t] = lo;
    }
    __syncthreads();
    const float c = (float)(bounds[1] - bounds[0]);
    sg[t] = gsum[b * 256 + t] / fmaxf(c, 1.0f);
    __syncthreads();
    float acc = bc1[t];
    for (int k = 0; k < 256; ++k) acc += sg[k] * Wc1[k * 256 + t];
    sh[t] = fmaxf(acc, 0.f);
    __syncthreads();
    if (t < 5) {
        float o = bc2[t];
        for (int k = 0; k < 256; ++k) o += sh[k] * Wc2[k * 5 + t];
        out[b * 5 + t] = o;
    }
}

// ===================== launch =====================

extern "C" void kernel_launch(void* const* d_in, const int* in_sizes, int n_in,
                              void* d_out, int out_size, void* d_ws, size_t ws_size,
                              hipStream_t stream) {
    const float* x    = (const float*)d_in[0];
    const int*   eidx = (const int*)d_in[1];
    const int*   batch= (const int*)d_in[2];
    const float* W0 = (const float*)d_in[3];  const float* b0 = (const float*)d_in[4];
    const float* W1 = (const float*)d_in[5];  const float* b1 = (const float*)d_in[6];
    const float* W2 = (const float*)d_in[7];  const float* b2 = (const float*)d_in[8];
    const float* Wc1= (const float*)d_in[9];  const float* bc1= (const float*)d_in[10];
    const float* Wc2= (const float*)d_in[11]; const float* bc2= (const float*)d_in[12];
    float* out = (float*)d_out;

    const int N   = in_sizes[2];       // 50000
    const int E   = in_sizes[1] / 2;   // 500000
    const int DIN = in_sizes[0] / N;   // 128
    const int DH  = in_sizes[4];       // 256
    const int* src = eidx;
    const int* dst = eidx + E;

    char* p = (char*)d_ws;
    auto alloc = [&](size_t bytes) {
        char* r = p;
        p += (bytes + 255) & ~(size_t)255;
        return (void*)r;
    };
    __half* hbuf = (__half*)alloc((size_t)N * DH * 2);   // gemm out (fp16), agg gather in
    __half* ha   = (__half*)alloc((size_t)N * DH * 2);   // agg out / gemm A in (fp16)
    __half* xh   = (__half*)alloc((size_t)N * DIN * 2);  // x in fp16
    __half* w0hi = (__half*)alloc((size_t)DH * DIN * 2);
    __half* w0lo = (__half*)alloc((size_t)DH * DIN * 2);
    __half* w1hi = (__half*)alloc((size_t)DH * DH * 2);
    __half* w1lo = (__half*)alloc((size_t)DH * DH * 2);
    __half* w2hi = (__half*)alloc((size_t)DH * DH * 2);
    __half* w2lo = (__half*)alloc((size_t)DH * DH * 2);
    int*   deg   = (int*)alloc((size_t)N * 4);
    float* gsum  = (float*)alloc(64 * (size_t)DH * 4);   // adjacent to deg: one memset covers both
    float* dinv  = (float*)alloc((size_t)N * 4);
    int*   part  = (int*)alloc((size_t)N * 4);
    int*   bsum  = (int*)alloc(256 * 4);
    int*   rowptr= (int*)alloc((size_t)(N + 1) * 4);
    int*   cursor= (int*)alloc((size_t)N * 4);
    edge_t* edg  = (edge_t*)alloc((size_t)E * 8);

    hipMemsetAsync(deg, 0, (size_t)((char*)gsum - (char*)deg) + 64 * (size_t)DH * 4, stream);

    const int nb = (N + 255) / 256;
    const int wtot = DIN * DH + 2 * DH * DH;
    const int wb = (wtot + 255) / 256;
    const int degB = (E + 1023) / 1024;
    const int nx = N * DIN;
    const int xb = (nx + 1023) / 1024;

    k_degx  <<<degB + xb, 256, 0, stream>>>(dst, E, deg, degB, x, xh, nx);
    k_scan1w<<<nb + wb, 256, 0, stream>>>(deg, N, nb, part, bsum, dinv,
                                          W0, w0hi, w0lo, W1, w1hi, w1lo, W2, w2hi, w2lo, DIN, DH);
    k_scan3 <<<nb, 256, 0, stream>>>(part, bsum, nb, N, E, rowptr, cursor);
    k_fill  <<<(E + 255) / 256, 256, 0, stream>>>(src, dst, E, dinv, cursor, edg);

    const int gemmBlocks = (N + 127) / 128;

    // layer 0: agg(x fp16) -> fp16 A -> gemm(relu(.W0+b0)) -> fp16 H
    k_agg128<<<(N + 7) / 8, 256, 0, stream>>>(xh, rowptr, edg, dinv, ha, N);
    k_gemm_mfma<<<gemmBlocks, 512, 0, stream>>>(ha, w0hi, w0lo, b0, hbuf, N, DIN);
    // layer 1
    k_agg256<<<(N + 3) / 4, 256, 0, stream>>>(hbuf, rowptr, edg, dinv, ha, N);
    k_gemm_mfma<<<gemmBlocks, 512, 0, stream>>>(ha, w1hi, w1lo, b1, hbuf, N, DH);
    // layer 2 (fused pooling epilogue)
    k_agg256<<<(N + 3) / 4, 256, 0, stream>>>(hbuf, rowptr, edg, dinv, ha, N);
    k_gemm_pool<<<gemmBlocks, 512, 0, stream>>>(ha, w2hi, w2lo, b2, batch, gsum, N, DH);

    k_poolcls<<<64, 256, 0, stream>>>(gsum, batch, N, Wc1, bc1, Wc2, bc2, out);
}

// Round 7
// 345.078 us; speedup vs baseline: 1.2034x; 1.0054x over previous
//
#include <hip/hip_runtime.h>
#include <hip/hip_fp16.h>

typedef _Float16 f16x8 __attribute__((ext_vector_type(8)));  // 8 fp16 = 4 VGPRs (MFMA A/B)
typedef float fx4 __attribute__((ext_vector_type(4)));       // MFMA acc

#define AS_G(p) ((const __attribute__((address_space(1))) void*)(p))
#define AS_L(p) ((__attribute__((address_space(3))) void*)(p))

struct __align__(8) half4 { __half2 lo, hi; };
struct __align__(8) edge_t { int u; float w; };   // paired edge record: one 8B store/load

// fp16 two-term split for weights: hi = fp16(w), lo = fp16(w - hi)  (combined ~2^-23 rel)
__device__ inline void split2h(float a, __half& hi, __half& lo) {
    hi = __float2half(a);
    lo = __float2half(a - __half2float(hi));
}

// ===================== graph preprocessing =====================

// fused dispatch: blocks [0,degB) histogram degrees (4 edges/thread); blocks [degB,..) x -> fp16.
__global__ void k_degx(const int* __restrict__ dst, int E, int* __restrict__ deg, int degB,
                       const float* __restrict__ x, __half* __restrict__ xh, int nx) {
    if (blockIdx.x < (unsigned)degB) {
        int i = (blockIdx.x * 256 + threadIdx.x) * 4;
        if (i + 4 <= E) {
            int4 d4 = *(const int4*)&dst[i];
            atomicAdd(&deg[d4.x], 1);
            atomicAdd(&deg[d4.y], 1);
            atomicAdd(&deg[d4.z], 1);
            atomicAdd(&deg[d4.w], 1);
        } else {
            for (int j = i; j < E; ++j) atomicAdd(&deg[dst[j]], 1);
        }
    } else {
        int i = (blockIdx.x - degB) * 1024 + threadIdx.x * 4;
        if (i < nx) {
            float4 v = *(const float4*)&x[i];
            __half2 h0(__float2half(v.x), __float2half(v.y));
            __half2 h1(__float2half(v.z), __float2half(v.w));
            *(__half2*)&xh[i] = h0;
            *(__half2*)&xh[i + 2] = h1;
        }
    }
}

// fused dispatch: blocks [0,nb) deg-scan + dinv; blocks [nb,..) split/transpose weights to fp16 hi/lo.
__global__ void k_scan1w(const int* __restrict__ deg, int N, int nb,
                         int* __restrict__ part, int* __restrict__ bsum, float* __restrict__ dinv,
                         const float* __restrict__ W0, __half* __restrict__ h0, __half* __restrict__ l0,
                         const float* __restrict__ W1, __half* __restrict__ h1, __half* __restrict__ l1,
                         const float* __restrict__ W2, __half* __restrict__ h2, __half* __restrict__ l2,
                         int DIN, int DH) {
    __shared__ int s[256];
    if (blockIdx.x < (unsigned)nb) {
        int i = blockIdx.x * 256 + threadIdx.x;
        int v = (i < N) ? deg[i] : 0;
        if (i < N) dinv[i] = 1.0f / sqrtf((float)(v + 1));  // +1 self-loop
        s[threadIdx.x] = v;
        __syncthreads();
        for (int off = 1; off < 256; off <<= 1) {
            int t = (threadIdx.x >= off) ? s[threadIdx.x - off] : 0;
            __syncthreads();
            s[threadIdx.x] += t;
            __syncthreads();
        }
        if (i < N) part[i] = s[threadIdx.x] - v;
        if (threadIdx.x == 255) bsum[blockIdx.x] = s[255];
    } else {
        int i = (blockIdx.x - nb) * 256 + threadIdx.x;
        const int n0 = DIN * DH, n1 = DH * DH;
        const float* W; __half *hT, *lT; int K, li;
        if (i < n0) { W = W0; hT = h0; lT = l0; K = DIN; li = i; }
        else if (i < n0 + n1) { W = W1; hT = h1; lT = l1; K = DH; li = i - n0; }
        else if (i < n0 + 2 * n1) { W = W2; hT = h2; lT = l2; K = DH; li = i - n0 - n1; }
        else return;
        int k = li / DH, n = li - k * DH;
        __half h, l;
        split2h(W[li], h, l);
        hT[(size_t)n * K + k] = h;
        lT[(size_t)n * K + k] = l;
    }
}

// rowptr build; each block reduces the raw per-block sums itself (nb <= 256).
__global__ void k_scan3(const int* __restrict__ part, const int* __restrict__ bsum, int nb,
                        int N, int E, int* __restrict__ rowptr, int* __restrict__ cursor) {
    __shared__ int s[256];
    const int t = threadIdx.x;
    s[t] = (t < nb && t < (int)blockIdx.x) ? bsum[t] : 0;
    __syncthreads();
    for (int off = 128; off > 0; off >>= 1) {
        if (t < off) s[t] += s[t + off];
        __syncthreads();
    }
    const int base = s[0];
    int i = blockIdx.x * 256 + t;
    if (i < N) {
        int v = part[i] + base;
        rowptr[i] = v;
        cursor[i] = v;
    }
    if (i == 0) rowptr[N] = E;
}

__global__ void k_fill(const int* __restrict__ src, const int* __restrict__ dst, int E,
                       const float* __restrict__ dinv, int* __restrict__ cursor,
                       edge_t* __restrict__ edg) {
    int e = blockIdx.x * blockDim.x + threadIdx.x;
    if (e < E) {
        int s = src[e], d = dst[e];
        int p = atomicAdd(&cursor[d], 1);
        edge_t ed;
        ed.u = s;
        ed.w = dinv[s] * dinv[d];
        edg[p] = ed;
    }
}

// ===================== fp16 MFMA GEMM, BN=256 (full output width per block) =============
// Block = 128 rows x 256 cols, 512 threads (8 waves, 2x4 wave grid of 64x64 tiles).
// r21: T4 counted-vmcnt pipeline (guide m218: counted-vs-drain0 is the lever; r20's
// __syncthreads dbuf was neutral because each barrier's implicit vmcnt(0) drained the
// just-issued stage). Two stages in flight (prologue: chunks 0,1); per iter:
//   s_waitcnt vmcnt(5)   <- own stage-t loads done; stage-(t+1)'s 5 keep flying
//   s_barrier            <- all waves' stage-t visible
//   compute buf[t&1]
//   s_barrier            <- all waves done reading buf[t&1]
//   stage chunk t+2 -> buf[t&1]
// vmcnt retires in issue order so the count is exact; tail waits vmcnt(0).
// sched_barrier(0) after each barrier pins the schedule (guide rule 18). Staging
// addresses / LDS image / fragment indices / accumulation order unchanged =>
// bit-identical C vs round-0.

__device__ __forceinline__ void gemm_core(
    const __half* __restrict__ Aop, const __half* __restrict__ BhiT, const __half* __restrict__ BloT,
    __half* smem, int Nrows, int K, int row0,
    int wid, int lane, int wrow, int wcol, int quad, int l16, fx4 (&acc)[4][4]) {
    // 40 1KB stage-slots per buffer: A 0..7 (128 rows), Bhi 8..23 (256 rows), Blo 24..39.
    const __half* gp[5];
    int ldsoff[5];
#pragma unroll
    for (int j = 0; j < 5; ++j) {
        int L = wid * 5 + j;
        int arr, slot;
        if (L < 8) { arr = 0; slot = L; }
        else if (L < 24) { arr = 1; slot = L - 8; }
        else { arr = 2; slot = L - 24; }
        int r = 16 * slot + (lane >> 2);
        int s = lane & 3;
        int q = (s - (r >> 1)) & 3;              // XOR swizzle folded into global addr
        const __half* garr = (arr == 0) ? Aop : (arr == 1) ? BhiT : BloT;
        int grow = (arr == 0) ? min(row0 + r, Nrows - 1) : r;
        gp[j] = garr + (size_t)grow * K + q * 8;
        ldsoff[j] = ((arr == 0) ? 0 : (arr == 1) ? 8192 : 24576) + slot * 1024;
    }

    int aidx[4], bidx[4];
#pragma unroll
    for (int t = 0; t < 4; ++t) {
        int ra = wrow * 64 + t * 16 + l16;
        aidx[t] = ra * 32 + ((quad + (ra >> 1)) & 3) * 8;
        int rb = wcol * 64 + t * 16 + l16;       // wcol in [0,4): covers 256 B-rows
        bidx[t] = rb * 32 + ((quad + (rb >> 1)) & 3) * 8;
    }

    const int NI = K >> 5;
    // prologue: two stages in flight (chunk 0 -> buf0, chunk 1 -> buf1)
#pragma unroll
    for (int j = 0; j < 5; ++j)
        __builtin_amdgcn_global_load_lds(AS_G(gp[j]), AS_L((char*)smem + ldsoff[j]), 16, 0, 0);
#pragma unroll
    for (int j = 0; j < 5; ++j)
        __builtin_amdgcn_global_load_lds(AS_G(gp[j] + 32), AS_L((char*)smem + 40960 + ldsoff[j]), 16, 0, 0);

    for (int it = 0; it < NI; ++it) {
        // wait for OWN stage-it loads only (5 of stage it+1 may remain in flight)
        if (it + 1 < NI) asm volatile("s_waitcnt vmcnt(5)" ::: "memory");
        else             asm volatile("s_waitcnt vmcnt(0)" ::: "memory");
        __builtin_amdgcn_s_barrier();            // all waves' stage-it visible
        __builtin_amdgcn_sched_barrier(0);

        const __half* buf  = smem + (it & 1) * 20480;   // 40KB buffer select (in halfs)
        const __half* sA   = buf;                       // 128 x 32
        const __half* sBhi = buf + 4096;                // 256 x 32
        const __half* sBlo = buf + 12288;               // 256 x 32

        f16x8 a[4];
#pragma unroll
        for (int mi = 0; mi < 4; ++mi) a[mi] = *(const f16x8*)&sA[aidx[mi]];
#pragma unroll
        for (int nj = 0; nj < 4; ++nj) {
            f16x8 bh = *(const f16x8*)&sBhi[bidx[nj]];
            f16x8 bl = *(const f16x8*)&sBlo[bidx[nj]];
#pragma unroll
            for (int mi = 0; mi < 4; ++mi) {
                acc[mi][nj] = __builtin_amdgcn_mfma_f32_16x16x32_f16(a[mi], bh, acc[mi][nj], 0, 0, 0);
                acc[mi][nj] = __builtin_amdgcn_mfma_f32_16x16x32_f16(a[mi], bl, acc[mi][nj], 0, 0, 0);
            }
        }

        __builtin_amdgcn_s_barrier();            // all waves done reading buf[it&1]
        __builtin_amdgcn_sched_barrier(0);

        // stage chunk it+2 into the buffer just consumed; it has the whole next
        // iteration (wait+barrier+compute+barrier) to cover its latency.
        if (it + 2 < NI) {
            const int koff = (it + 2) * 32;
            const int boff = (it & 1) * 40960;
#pragma unroll
            for (int j = 0; j < 5; ++j)
                __builtin_amdgcn_global_load_lds(AS_G(gp[j] + koff),
                    AS_L((char*)smem + boff + ldsoff[j]), 16, 0, 0);
        }
    }
}

__global__ __launch_bounds__(512) void k_gemm_mfma(
    const __half* __restrict__ Aop, const __half* __restrict__ BhiT, const __half* __restrict__ BloT,
    const float* __restrict__ bias, __half* __restrict__ C, int Nrows, int K) {
    __shared__ __align__(16) __half smem[40960];   // 80 KB: 2 x 40KB stage buffers
    const int tid = threadIdx.x;
    const int wid = tid >> 6, lane = tid & 63;
    const int row0 = blockIdx.x * 128;
    const int wrow = wid & 1, wcol = wid >> 1;     // 2 x 4 wave grid
    const int quad = lane >> 4, l16 = lane & 15;

    fx4 acc[4][4] = {};
    gemm_core(Aop, BhiT, BloT, smem, Nrows, K, row0, wid, lane, wrow, wcol, quad, l16, acc);

    // C/D layout: col = lane&15, row = quad*4 + reg  [m89-verified, dtype-independent]
#pragma unroll
    for (int mi = 0; mi < 4; ++mi) {
        const int rbase = row0 + wrow * 64 + mi * 16 + quad * 4;
#pragma unroll
        for (int nj = 0; nj < 4; ++nj) {
            const int c = wcol * 64 + nj * 16 + l16;
            const float bc = bias[c];
#pragma unroll
            for (int reg = 0; reg < 4; ++reg) {
                int r = rbase + reg;
                if (r < Nrows) C[(size_t)r * 256 + c] = __float2half(fmaxf(acc[mi][nj][reg] + bc, 0.f));
            }
        }
    }
}

// Layer-2 variant: relu(acc+bias) pooled per-graph into gsum[64][256]
__global__ __launch_bounds__(512) void k_gemm_pool(
    const __half* __restrict__ Aop, const __half* __restrict__ BhiT, const __half* __restrict__ BloT,
    const float* __restrict__ bias, const int* __restrict__ batch,
    float* __restrict__ gsum, int Nrows, int K) {
    __shared__ __align__(16) __half smem[40960];
    const int tid = threadIdx.x;
    const int wid = tid >> 6, lane = tid & 63;
    const int row0 = blockIdx.x * 128;
    const int wrow = wid & 1, wcol = wid >> 1;
    const int quad = lane >> 4, l16 = lane & 15;

    fx4 acc[4][4] = {};
    gemm_core(Aop, BhiT, BloT, smem, Nrows, K, row0, wid, lane, wrow, wcol, quad, l16, acc);

    int bg[4][4];
#pragma unroll
    for (int mi = 0; mi < 4; ++mi)
#pragma unroll
        for (int reg = 0; reg < 4; ++reg) {
            int r = row0 + wrow * 64 + mi * 16 + quad * 4 + reg;
            bg[mi][reg] = (r < Nrows) ? batch[r] : -1;
        }
    const int gfirst = batch[row0 < Nrows ? row0 : (Nrows - 1)];
    const int glast  = batch[min(row0 + 127, Nrows - 1)];

#pragma unroll
    for (int nj = 0; nj < 4; ++nj) {
        const int c = wcol * 64 + nj * 16 + l16;
        const float bc = bias[c];
        for (int g = gfirst; g <= glast; ++g) {
            float s = 0.f;
#pragma unroll
            for (int mi = 0; mi < 4; ++mi)
#pragma unroll
                for (int reg = 0; reg < 4; ++reg)
                    if (bg[mi][reg] == g) s += fmaxf(acc[mi][nj][reg] + bc, 0.f);
            s += __shfl_xor(s, 16);
            s += __shfl_xor(s, 32);
            if (quad == 0) atomicAdd(&gsum[g * 256 + c], s);
        }
    }
}

// ===================== aggregation (fp16 gather, fp32 accumulate, fp16 out) =============
// WAVE-PER-NODE, r14 inner loop + fixed grid — proven best (339.5us round-0). r15
// (predication), r16 (persistent), r17 (gemm overlap) all regressed or neutral:
// throughput pinned by per-CU outstanding-request capacity at ~3.4 TB/s for this
// random-512B pattern, insensitive to occupancy/MLP levers. Do not touch.

__global__ __launch_bounds__(256) void k_agg256(const __half* __restrict__ H, const int* __restrict__ rowptr,
                                                const edge_t* __restrict__ edg,
                                                const float* __restrict__ dinv,
                                                __half* __restrict__ outA, int N) {
    const int wave = threadIdx.x >> 6, lane = threadIdx.x & 63;
    const int v = blockIdx.x * 4 + wave;
    if (v >= N) return;

    const float di = dinv[v];
    const float selfn = di * di;
    half4 hv = ((const half4*)&H[(size_t)v * 256])[lane];
    float2 s0 = __half22float2(hv.lo), s1 = __half22float2(hv.hi);
    float ax = selfn * s0.x, ay = selfn * s0.y, az = selfn * s1.x, aw = selfn * s1.y;

    int e = rowptr[v];
    const int end = rowptr[v + 1];
    for (; e + 8 <= end; e += 8) {
        edge_t ed[8]; half4 g[8];
#pragma unroll
        for (int j = 0; j < 8; ++j) ed[j] = edg[e + j];
#pragma unroll
        for (int j = 0; j < 8; ++j) g[j] = ((const half4*)&H[(size_t)ed[j].u * 256])[lane];
#pragma unroll
        for (int j = 0; j < 8; ++j) {
            float2 f0 = __half22float2(g[j].lo), f1 = __half22float2(g[j].hi);
            ax += ed[j].w * f0.x; ay += ed[j].w * f0.y; az += ed[j].w * f1.x; aw += ed[j].w * f1.y;
        }
    }
    for (; e < end; ++e) {
        edge_t ed = edg[e];
        half4 g = ((const half4*)&H[(size_t)ed.u * 256])[lane];
        float2 f0 = __half22float2(g.lo), f1 = __half22float2(g.hi);
        ax += ed.w * f0.x; ay += ed.w * f0.y; az += ed.w * f1.x; aw += ed.w * f1.y;
    }

    half4 o;
    o.lo = __floats2half2_rn(ax, ay);
    o.hi = __floats2half2_rn(az, aw);
    ((half4*)outA)[(size_t)v * 64 + lane] = o;
}

__global__ __launch_bounds__(256) void k_agg128(const __half* __restrict__ X, const int* __restrict__ rowptr,
                                                const edge_t* __restrict__ edg,
                                                const float* __restrict__ dinv,
                                                __half* __restrict__ outA, int N) {
    const int half = threadIdx.x >> 5, sub = threadIdx.x & 31;
    const int v = blockIdx.x * 8 + half;
    if (v >= N) return;

    const float di = dinv[v];
    const float selfn = di * di;
    half4 hv = ((const half4*)&X[(size_t)v * 128])[sub];
    float2 s0 = __half22float2(hv.lo), s1 = __half22float2(hv.hi);
    float ax = selfn * s0.x, ay = selfn * s0.y, az = selfn * s1.x, aw = selfn * s1.y;

    int e = rowptr[v];
    const int end = rowptr[v + 1];
    for (; e + 4 <= end; e += 4) {
        edge_t ed[4]; half4 g[4];
#pragma unroll
        for (int j = 0; j < 4; ++j) ed[j] = edg[e + j];
#pragma unroll
        for (int j = 0; j < 4; ++j) g[j] = ((const half4*)&X[(size_t)ed[j].u * 128])[sub];
#pragma unroll
        for (int j = 0; j < 4; ++j) {
            float2 f0 = __half22float2(g[j].lo), f1 = __half22float2(g[j].hi);
            ax += ed[j].w * f0.x; ay += ed[j].w * f0.y; az += ed[j].w * f1.x; aw += ed[j].w * f1.y;
        }
    }
    for (; e < end; ++e) {
        edge_t ed = edg[e];
        half4 g = ((const half4*)&X[(size_t)ed.u * 128])[sub];
        float2 f0 = __half22float2(g.lo), f1 = __half22float2(g.hi);
        ax += ed.w * f0.x; ay += ed.w * f0.y; az += ed.w * f1.x; aw += ed.w * f1.y;
    }

    half4 o;
    o.lo = __floats2half2_rn(ax, ay);
    o.hi = __floats2half2_rn(az, aw);
    ((half4*)outA)[(size_t)v * 32 + sub] = o;
}

// ===================== fused mean-pool finalize + classifier head =====================

__global__ __launch_bounds__(256) void k_poolcls(const float* __restrict__ gsum, const int* __restrict__ batch,
                                                 int N,
                                                 const float* __restrict__ Wc1, const float* __restrict__ bc1,
                                                 const float* __restrict__ Wc2, const float* __restrict__ bc2,
                                                 float* __restrict__ out) {
    __shared__ float sg[256], sh[256];
    __shared__ int bounds[2];
    const int b = blockIdx.x, t = threadIdx.x;
    if (t < 2) {
        int target = b + t;
        int lo = 0, hi = N;
        while (lo < hi) {
            int mid = (lo + hi) >> 1;
            if (batch[mid] < target) lo = mid + 1; else hi = mid;
        }
        bounds[t] = lo;
    }
    __syncthreads();
    const float c = (float)(bounds[1] - bounds[0]);
    sg[t] = gsum[b * 256 + t] / fmaxf(c, 1.0f);
    __syncthreads();
    float acc = bc1[t];
    for (int k = 0; k < 256; ++k) acc += sg[k] * Wc1[k * 256 + t];
    sh[t] = fmaxf(acc, 0.f);
    __syncthreads();
    if (t < 5) {
        float o = bc2[t];
        for (int k = 0; k < 256; ++k) o += sh[k] * Wc2[k * 5 + t];
        out[b * 5 + t] = o;
    }
}

// ===================== launch =====================

extern "C" void kernel_launch(void* const* d_in, const int* in_sizes, int n_in,
                              void* d_out, int out_size, void* d_ws, size_t ws_size,
                              hipStream_t stream) {
    const float* x    = (const float*)d_in[0];
    const int*   eidx = (const int*)d_in[1];
    const int*   batch= (const int*)d_in[2];
    const float* W0 = (const float*)d_in[3];  const float* b0 = (const float*)d_in[4];
    const float* W1 = (const float*)d_in[5];  const float* b1 = (const float*)d_in[6];
    const float* W2 = (const float*)d_in[7];  const float* b2 = (const float*)d_in[8];
    const float* Wc1= (const float*)d_in[9];  const float* bc1= (const float*)d_in[10];
    const float* Wc2= (const float*)d_in[11]; const float* bc2= (const float*)d_in[12];
    float* out = (float*)d_out;

    const int N   = in_sizes[2];       // 50000
    const int E   = in_sizes[1] / 2;   // 500000
    const int DIN = in_sizes[0] / N;   // 128
    const int DH  = in_sizes[4];       // 256
    const int* src = eidx;
    const int* dst = eidx + E;

    char* p = (char*)d_ws;
    auto alloc = [&](size_t bytes) {
        char* r = p;
        p += (bytes + 255) & ~(size_t)255;
        return (void*)r;
    };
    __half* hbuf = (__half*)alloc((size_t)N * DH * 2);   // gemm out (fp16), agg gather in
    __half* ha   = (__half*)alloc((size_t)N * DH * 2);   // agg out / gemm A in (fp16)
    __half* xh   = (__half*)alloc((size_t)N * DIN * 2);  // x in fp16
    __half* w0hi = (__half*)alloc((size_t)DH * DIN * 2);
    __half* w0lo = (__half*)alloc((size_t)DH * DIN * 2);
    __half* w1hi = (__half*)alloc((size_t)DH * DH * 2);
    __half* w1lo = (__half*)alloc((size_t)DH * DH * 2);
    __half* w2hi = (__half*)alloc((size_t)DH * DH * 2);
    __half* w2lo = (__half*)alloc((size_t)DH * DH * 2);
    int*   deg   = (int*)alloc((size_t)N * 4);
    float* gsum  = (float*)alloc(64 * (size_t)DH * 4);   // adjacent to deg: one memset covers both
    float* dinv  = (float*)alloc((size_t)N * 4);
    int*   part  = (int*)alloc((size_t)N * 4);
    int*   bsum  = (int*)alloc(256 * 4);
    int*   rowptr= (int*)alloc((size_t)(N + 1) * 4);
    int*   cursor= (int*)alloc((size_t)N * 4);
    edge_t* edg  = (edge_t*)alloc((size_t)E * 8);

    hipMemsetAsync(deg, 0, (size_t)((char*)gsum - (char*)deg) + 64 * (size_t)DH * 4, stream);

    const int nb = (N + 255) / 256;
    const int wtot = DIN * DH + 2 * DH * DH;
    const int wb = (wtot + 255) / 256;
    const int degB = (E + 1023) / 1024;
    const int nx = N * DIN;
    const int xb = (nx + 1023) / 1024;

    k_degx  <<<degB + xb, 256, 0, stream>>>(dst, E, deg, degB, x, xh, nx);
    k_scan1w<<<nb + wb, 256, 0, stream>>>(deg, N, nb, part, bsum, dinv,
                                          W0, w0hi, w0lo, W1, w1hi, w1lo, W2, w2hi, w2lo, DIN, DH);
    k_scan3 <<<nb, 256, 0, stream>>>(part, bsum, nb, N, E, rowptr, cursor);
    k_fill  <<<(E + 255) / 256, 256, 0, stream>>>(src, dst, E, dinv, cursor, edg);

    const int gemmBlocks = (N + 127) / 128;

    // layer 0: agg(x fp16) -> fp16 A -> gemm(relu(.W0+b0)) -> fp16 H
    k_agg128<<<(N + 7) / 8, 256, 0, stream>>>(xh, rowptr, edg, dinv, ha, N);
    k_gemm_mfma<<<gemmBlocks, 512, 0, stream>>>(ha, w0hi, w0lo, b0, hbuf, N, DIN);
    // layer 1
    k_agg256<<<(N + 3) / 4, 256, 0, stream>>>(hbuf, rowptr, edg, dinv, ha, N);
    k_gemm_mfma<<<gemmBlocks, 512, 0, stream>>>(ha, w1hi, w1lo, b1, hbuf, N, DH);
    // layer 2 (fused pooling epilogue)
    k_agg256<<<(N + 3) / 4, 256, 0, stream>>>(hbuf, rowptr, edg, dinv, ha, N);
    k_gemm_pool<<<gemmBlocks, 512, 0, stream>>>(ha, w2hi, w2lo, b2, batch, gsum, N, DH);

    k_poolcls<<<64, 256, 0, stream>>>(gsum, batch, N, Wc1, bc1, Wc2, bc2, out);
}

// Round 8
// 340.937 us; speedup vs baseline: 1.2180x; 1.0121x over previous
//
#include <hip/hip_runtime.h>
#include <hip/hip_fp16.h>

typedef _Float16 f16x8 __attribute__((ext_vector_type(8)));  // 8 fp16 = 4 VGPRs (MFMA A/B)
typedef float fx4 __attribute__((ext_vector_type(4)));       // MFMA acc

#define AS_G(p) ((const __attribute__((address_space(1))) void*)(p))
#define AS_L(p) ((__attribute__((address_space(3))) void*)(p))

struct __align__(8) half4 { __half2 lo, hi; };
struct __align__(8) edge_t { int u; float w; };   // paired edge record: one 8B store/load

// fp16 two-term split for weights: hi = fp16(w), lo = fp16(w - hi)  (combined ~2^-23 rel)
__device__ inline void split2h(float a, __half& hi, __half& lo) {
    hi = __float2half(a);
    lo = __float2half(a - __half2float(hi));
}

// ===================== graph preprocessing =====================

// fused dispatch: blocks [0,degB) histogram degrees (4 edges/thread); blocks [degB,..) x -> fp16.
__global__ void k_degx(const int* __restrict__ dst, int E, int* __restrict__ deg, int degB,
                       const float* __restrict__ x, __half* __restrict__ xh, int nx) {
    if (blockIdx.x < (unsigned)degB) {
        int i = (blockIdx.x * 256 + threadIdx.x) * 4;
        if (i + 4 <= E) {
            int4 d4 = *(const int4*)&dst[i];
            atomicAdd(&deg[d4.x], 1);
            atomicAdd(&deg[d4.y], 1);
            atomicAdd(&deg[d4.z], 1);
            atomicAdd(&deg[d4.w], 1);
        } else {
            for (int j = i; j < E; ++j) atomicAdd(&deg[dst[j]], 1);
        }
    } else {
        int i = (blockIdx.x - degB) * 1024 + threadIdx.x * 4;
        if (i < nx) {
            float4 v = *(const float4*)&x[i];
            __half2 h0(__float2half(v.x), __float2half(v.y));
            __half2 h1(__float2half(v.z), __float2half(v.w));
            *(__half2*)&xh[i] = h0;
            *(__half2*)&xh[i + 2] = h1;
        }
    }
}

// fused dispatch: blocks [0,nb) deg-scan + dinv; blocks [nb,..) split/transpose weights to fp16 hi/lo.
__global__ void k_scan1w(const int* __restrict__ deg, int N, int nb,
                         int* __restrict__ part, int* __restrict__ bsum, float* __restrict__ dinv,
                         const float* __restrict__ W0, __half* __restrict__ h0, __half* __restrict__ l0,
                         const float* __restrict__ W1, __half* __restrict__ h1, __half* __restrict__ l1,
                         const float* __restrict__ W2, __half* __restrict__ h2, __half* __restrict__ l2,
                         int DIN, int DH) {
    __shared__ int s[256];
    if (blockIdx.x < (unsigned)nb) {
        int i = blockIdx.x * 256 + threadIdx.x;
        int v = (i < N) ? deg[i] : 0;
        if (i < N) dinv[i] = 1.0f / sqrtf((float)(v + 1));  // +1 self-loop
        s[threadIdx.x] = v;
        __syncthreads();
        for (int off = 1; off < 256; off <<= 1) {
            int t = (threadIdx.x >= off) ? s[threadIdx.x - off] : 0;
            __syncthreads();
            s[threadIdx.x] += t;
            __syncthreads();
        }
        if (i < N) part[i] = s[threadIdx.x] - v;
        if (threadIdx.x == 255) bsum[blockIdx.x] = s[255];
    } else {
        int i = (blockIdx.x - nb) * 256 + threadIdx.x;
        const int n0 = DIN * DH, n1 = DH * DH;
        const float* W; __half *hT, *lT; int K, li;
        if (i < n0) { W = W0; hT = h0; lT = l0; K = DIN; li = i; }
        else if (i < n0 + n1) { W = W1; hT = h1; lT = l1; K = DH; li = i - n0; }
        else if (i < n0 + 2 * n1) { W = W2; hT = h2; lT = l2; K = DH; li = i - n0 - n1; }
        else return;
        int k = li / DH, n = li - k * DH;
        __half h, l;
        split2h(W[li], h, l);
        hT[(size_t)n * K + k] = h;
        lT[(size_t)n * K + k] = l;
    }
}

// rowptr build; each block reduces the raw per-block sums itself (nb <= 256).
__global__ void k_scan3(const int* __restrict__ part, const int* __restrict__ bsum, int nb,
                        int N, int E, int* __restrict__ rowptr, int* __restrict__ cursor) {
    __shared__ int s[256];
    const int t = threadIdx.x;
    s[t] = (t < nb && t < (int)blockIdx.x) ? bsum[t] : 0;
    __syncthreads();
    for (int off = 128; off > 0; off >>= 1) {
        if (t < off) s[t] += s[t + off];
        __syncthreads();
    }
    const int base = s[0];
    int i = blockIdx.x * 256 + t;
    if (i < N) {
        int v = part[i] + base;
        rowptr[i] = v;
        cursor[i] = v;
    }
    if (i == 0) rowptr[N] = E;
}

__global__ void k_fill(const int* __restrict__ src, const int* __restrict__ dst, int E,
                       const float* __restrict__ dinv, int* __restrict__ cursor,
                       edge_t* __restrict__ edg) {
    int e = blockIdx.x * blockDim.x + threadIdx.x;
    if (e < E) {
        int s = src[e], d = dst[e];
        int p = atomicAdd(&cursor[d], 1);
        edge_t ed;
        ed.u = s;
        ed.w = dinv[s] * dinv[d];
        edg[p] = ed;
    }
}

// ===================== fp16 MFMA GEMM, BN=256 (full output width per block) =============
// Block = 128 rows x 256 cols, 512 threads (8 waves, 2 row-groups x 4 col-groups of
// 64x64 wave tiles). A-rows fetched ONCE per layer. Single-buffered 40KB LDS.
// PROVEN OPTIMUM of this structure: r18 (64-row tile) -10us/gemm, r19 (B-direct,
// uncoalesced) -25us/gemm, r20 (dbuf+syncthreads) neutral, r21 (counted vmcnt, 2 stages
// in flight) neutral — at 2 blocks/CU the inter-block TLP already covers stage latency
// (m114); source-level pipelining of this short-K GEMM adds nothing. Do not touch.

__device__ __forceinline__ void gemm_core(
    const __half* __restrict__ Aop, const __half* __restrict__ BhiT, const __half* __restrict__ BloT,
    __half* smem, int Nrows, int K, int row0,
    int wid, int lane, int wrow, int wcol, int quad, int l16, fx4 (&acc)[4][4]) {
    // 40 1KB stage-slots: A 0..7 (128 rows), Bhi 8..23 (256 rows), Blo 24..39.
    const __half* gp[5];
    int ldsoff[5];
#pragma unroll
    for (int j = 0; j < 5; ++j) {
        int L = wid * 5 + j;
        int arr, slot;
        if (L < 8) { arr = 0; slot = L; }
        else if (L < 24) { arr = 1; slot = L - 8; }
        else { arr = 2; slot = L - 24; }
        int r = 16 * slot + (lane >> 2);
        int s = lane & 3;
        int q = (s - (r >> 1)) & 3;              // XOR swizzle folded into global addr
        const __half* garr = (arr == 0) ? Aop : (arr == 1) ? BhiT : BloT;
        int grow = (arr == 0) ? min(row0 + r, Nrows - 1) : r;
        gp[j] = garr + (size_t)grow * K + q * 8;
        ldsoff[j] = ((arr == 0) ? 0 : (arr == 1) ? 8192 : 24576) + slot * 1024;
    }

    const __half* sA   = smem;                   // 128 x 32
    const __half* sBhi = smem + 4096;            // 256 x 32 (byte off 8192)
    const __half* sBlo = smem + 12288;           // 256 x 32 (byte off 24576)

    int aidx[4], bidx[4];
#pragma unroll
    for (int t = 0; t < 4; ++t) {
        int ra = wrow * 64 + t * 16 + l16;
        aidx[t] = ra * 32 + ((quad + (ra >> 1)) & 3) * 8;
        int rb = wcol * 64 + t * 16 + l16;       // wcol in [0,4): covers 256 B-rows
        bidx[t] = rb * 32 + ((quad + (rb >> 1)) & 3) * 8;
    }

    for (int k0 = 0; k0 < K; k0 += 32) {
#pragma unroll
        for (int j = 0; j < 5; ++j)
            __builtin_amdgcn_global_load_lds(AS_G(gp[j] + k0), AS_L((char*)smem + ldsoff[j]), 16, 0, 0);
        __syncthreads();

        f16x8 a[4];
#pragma unroll
        for (int mi = 0; mi < 4; ++mi) a[mi] = *(const f16x8*)&sA[aidx[mi]];
#pragma unroll
        for (int nj = 0; nj < 4; ++nj) {
            f16x8 bh = *(const f16x8*)&sBhi[bidx[nj]];
            f16x8 bl = *(const f16x8*)&sBlo[bidx[nj]];
#pragma unroll
            for (int mi = 0; mi < 4; ++mi) {
                acc[mi][nj] = __builtin_amdgcn_mfma_f32_16x16x32_f16(a[mi], bh, acc[mi][nj], 0, 0, 0);
                acc[mi][nj] = __builtin_amdgcn_mfma_f32_16x16x32_f16(a[mi], bl, acc[mi][nj], 0, 0, 0);
            }
        }
        __syncthreads();
    }
}

__global__ __launch_bounds__(512) void k_gemm_mfma(
    const __half* __restrict__ Aop, const __half* __restrict__ BhiT, const __half* __restrict__ BloT,
    const float* __restrict__ bias, __half* __restrict__ C, int Nrows, int K) {
    __shared__ __align__(16) __half smem[20480];   // 40 KB
    const int tid = threadIdx.x;
    const int wid = tid >> 6, lane = tid & 63;
    const int row0 = blockIdx.x * 128;
    const int wrow = wid & 1, wcol = wid >> 1;     // 2 x 4 wave grid
    const int quad = lane >> 4, l16 = lane & 15;

    fx4 acc[4][4] = {};
    gemm_core(Aop, BhiT, BloT, smem, Nrows, K, row0, wid, lane, wrow, wcol, quad, l16, acc);

    // C/D layout: col = lane&15, row = quad*4 + reg  [m89-verified, dtype-independent]
#pragma unroll
    for (int mi = 0; mi < 4; ++mi) {
        const int rbase = row0 + wrow * 64 + mi * 16 + quad * 4;
#pragma unroll
        for (int nj = 0; nj < 4; ++nj) {
            const int c = wcol * 64 + nj * 16 + l16;
            const float bc = bias[c];
#pragma unroll
            for (int reg = 0; reg < 4; ++reg) {
                int r = rbase + reg;
                if (r < Nrows) C[(size_t)r * 256 + c] = __float2half(fmaxf(acc[mi][nj][reg] + bc, 0.f));
            }
        }
    }
}

// Layer-2 variant: relu(acc+bias) pooled per-graph into gsum[64][256]
__global__ __launch_bounds__(512) void k_gemm_pool(
    const __half* __restrict__ Aop, const __half* __restrict__ BhiT, const __half* __restrict__ BloT,
    const float* __restrict__ bias, const int* __restrict__ batch,
    float* __restrict__ gsum, int Nrows, int K) {
    __shared__ __align__(16) __half smem[20480];
    const int tid = threadIdx.x;
    const int wid = tid >> 6, lane = tid & 63;
    const int row0 = blockIdx.x * 128;
    const int wrow = wid & 1, wcol = wid >> 1;
    const int quad = lane >> 4, l16 = lane & 15;

    fx4 acc[4][4] = {};
    gemm_core(Aop, BhiT, BloT, smem, Nrows, K, row0, wid, lane, wrow, wcol, quad, l16, acc);

    int bg[4][4];
#pragma unroll
    for (int mi = 0; mi < 4; ++mi)
#pragma unroll
        for (int reg = 0; reg < 4; ++reg) {
            int r = row0 + wrow * 64 + mi * 16 + quad * 4 + reg;
            bg[mi][reg] = (r < Nrows) ? batch[r] : -1;
        }
    const int gfirst = batch[row0 < Nrows ? row0 : (Nrows - 1)];
    const int glast  = batch[min(row0 + 127, Nrows - 1)];

#pragma unroll
    for (int nj = 0; nj < 4; ++nj) {
        const int c = wcol * 64 + nj * 16 + l16;
        const float bc = bias[c];
        for (int g = gfirst; g <= glast; ++g) {
            float s = 0.f;
#pragma unroll
            for (int mi = 0; mi < 4; ++mi)
#pragma unroll
                for (int reg = 0; reg < 4; ++reg)
                    if (bg[mi][reg] == g) s += fmaxf(acc[mi][nj][reg] + bc, 0.f);
            s += __shfl_xor(s, 16);
            s += __shfl_xor(s, 32);
            if (quad == 0) atomicAdd(&gsum[g * 256 + c], s);
        }
    }
}

// ===================== aggregation (fp16 gather, fp32 accumulate, fp16 out) =============
// WAVE-PER-NODE, proven best. At the mixed-hierarchy delivered-BW roofline:
// ~311MB (gathers 256 + self 25.6 + records 4 + writes 25.6) / 44.9us ~= 6.9 TB/s
// aggregate (above the 6.3 TB/s HBM-copy ceiling; ~half served from L2/L3).
// Insensitive to MLP shaping (r15), occupancy (r16), co-scheduling (r17). Do not touch.

__global__ __launch_bounds__(256) void k_agg256(const __half* __restrict__ H, const int* __restrict__ rowptr,
                                                const edge_t* __restrict__ edg,
                                                const float* __restrict__ dinv,
                                                __half* __restrict__ outA, int N) {
    const int wave = threadIdx.x >> 6, lane = threadIdx.x & 63;
    const int v = blockIdx.x * 4 + wave;
    if (v >= N) return;

    const float di = dinv[v];
    const float selfn = di * di;
    half4 hv = ((const half4*)&H[(size_t)v * 256])[lane];
    float2 s0 = __half22float2(hv.lo), s1 = __half22float2(hv.hi);
    float ax = selfn * s0.x, ay = selfn * s0.y, az = selfn * s1.x, aw = selfn * s1.y;

    int e = rowptr[v];
    const int end = rowptr[v + 1];
    for (; e + 8 <= end; e += 8) {
        edge_t ed[8]; half4 g[8];
#pragma unroll
        for (int j = 0; j < 8; ++j) ed[j] = edg[e + j];
#pragma unroll
        for (int j = 0; j < 8; ++j) g[j] = ((const half4*)&H[(size_t)ed[j].u * 256])[lane];
#pragma unroll
        for (int j = 0; j < 8; ++j) {
            float2 f0 = __half22float2(g[j].lo), f1 = __half22float2(g[j].hi);
            ax += ed[j].w * f0.x; ay += ed[j].w * f0.y; az += ed[j].w * f1.x; aw += ed[j].w * f1.y;
        }
    }
    for (; e < end; ++e) {
        edge_t ed = edg[e];
        half4 g = ((const half4*)&H[(size_t)ed.u * 256])[lane];
        float2 f0 = __half22float2(g.lo), f1 = __half22float2(g.hi);
        ax += ed.w * f0.x; ay += ed.w * f0.y; az += ed.w * f1.x; aw += ed.w * f1.y;
    }

    half4 o;
    o.lo = __floats2half2_rn(ax, ay);
    o.hi = __floats2half2_rn(az, aw);
    ((half4*)outA)[(size_t)v * 64 + lane] = o;
}

__global__ __launch_bounds__(256) void k_agg128(const __half* __restrict__ X, const int* __restrict__ rowptr,
                                                const edge_t* __restrict__ edg,
                                                const float* __restrict__ dinv,
                                                __half* __restrict__ outA, int N) {
    const int half = threadIdx.x >> 5, sub = threadIdx.x & 31;
    const int v = blockIdx.x * 8 + half;
    if (v >= N) return;

    const float di = dinv[v];
    const float selfn = di * di;
    half4 hv = ((const half4*)&X[(size_t)v * 128])[sub];
    float2 s0 = __half22float2(hv.lo), s1 = __half22float2(hv.hi);
    float ax = selfn * s0.x, ay = selfn * s0.y, az = selfn * s1.x, aw = selfn * s1.y;

    int e = rowptr[v];
    const int end = rowptr[v + 1];
    for (; e + 4 <= end; e += 4) {
        edge_t ed[4]; half4 g[4];
#pragma unroll
        for (int j = 0; j < 4; ++j) ed[j] = edg[e + j];
#pragma unroll
        for (int j = 0; j < 4; ++j) g[j] = ((const half4*)&X[(size_t)ed[j].u * 128])[sub];
#pragma unroll
        for (int j = 0; j < 4; ++j) {
            float2 f0 = __half22float2(g[j].lo), f1 = __half22float2(g[j].hi);
            ax += ed[j].w * f0.x; ay += ed[j].w * f0.y; az += ed[j].w * f1.x; aw += ed[j].w * f1.y;
        }
    }
    for (; e < end; ++e) {
        edge_t ed = edg[e];
        half4 g = ((const half4*)&X[(size_t)ed.u * 128])[sub];
        float2 f0 = __half22float2(g.lo), f1 = __half22float2(g.hi);
        ax += ed.w * f0.x; ay += ed.w * f0.y; az += ed.w * f1.x; aw += ed.w * f1.y;
    }

    half4 o;
    o.lo = __floats2half2_rn(ax, ay);
    o.hi = __floats2half2_rn(az, aw);
    ((half4*)outA)[(size_t)v * 32 + sub] = o;
}

// ===================== fused mean-pool finalize + classifier head =====================

__global__ __launch_bounds__(256) void k_poolcls(const float* __restrict__ gsum, const int* __restrict__ batch,
                                                 int N,
                                                 const float* __restrict__ Wc1, const float* __restrict__ bc1,
                                                 const float* __restrict__ Wc2, const float* __restrict__ bc2,
                                                 float* __restrict__ out) {
    __shared__ float sg[256], sh[256];
    __shared__ int bounds[2];
    const int b = blockIdx.x, t = threadIdx.x;
    if (t < 2) {
        int target = b + t;
        int lo = 0, hi = N;
        while (lo < hi) {
            int mid = (lo + hi) >> 1;
            if (batch[mid] < target) lo = mid + 1; else hi = mid;
        }
        bounds[t] = lo;
    }
    __syncthreads();
    const float c = (float)(bounds[1] - bounds[0]);
    sg[t] = gsum[b * 256 + t] / fmaxf(c, 1.0f);
    __syncthreads();
    float acc = bc1[t];
    for (int k = 0; k < 256; ++k) acc += sg[k] * Wc1[k * 256 + t];
    sh[t] = fmaxf(acc, 0.f);
    __syncthreads();
    if (t < 5) {
        float o = bc2[t];
        for (int k = 0; k < 256; ++k) o += sh[k] * Wc2[k * 5 + t];
        out[b * 5 + t] = o;
    }
}

// ===================== launch =====================

extern "C" void kernel_launch(void* const* d_in, const int* in_sizes, int n_in,
                              void* d_out, int out_size, void* d_ws, size_t ws_size,
                              hipStream_t stream) {
    const float* x    = (const float*)d_in[0];
    const int*   eidx = (const int*)d_in[1];
    const int*   batch= (const int*)d_in[2];
    const float* W0 = (const float*)d_in[3];  const float* b0 = (const float*)d_in[4];
    const float* W1 = (const float*)d_in[5];  const float* b1 = (const float*)d_in[6];
    const float* W2 = (const float*)d_in[7];  const float* b2 = (const float*)d_in[8];
    const float* Wc1= (const float*)d_in[9];  const float* bc1= (const float*)d_in[10];
    const float* Wc2= (const float*)d_in[11]; const float* bc2= (const float*)d_in[12];
    float* out = (float*)d_out;

    const int N   = in_sizes[2];       // 50000
    const int E   = in_sizes[1] / 2;   // 500000
    const int DIN = in_sizes[0] / N;   // 128
    const int DH  = in_sizes[4];       // 256
    const int* src = eidx;
    const int* dst = eidx + E;

    char* p = (char*)d_ws;
    auto alloc = [&](size_t bytes) {
        char* r = p;
        p += (bytes + 255) & ~(size_t)255;
        return (void*)r;
    };
    __half* hbuf = (__half*)alloc((size_t)N * DH * 2);   // gemm out (fp16), agg gather in
    __half* ha   = (__half*)alloc((size_t)N * DH * 2);   // agg out / gemm A in (fp16)
    __half* xh   = (__half*)alloc((size_t)N * DIN * 2);  // x in fp16
    __half* w0hi = (__half*)alloc((size_t)DH * DIN * 2);
    __half* w0lo = (__half*)alloc((size_t)DH * DIN * 2);
    __half* w1hi = (__half*)alloc((size_t)DH * DH * 2);
    __half* w1lo = (__half*)alloc((size_t)DH * DH * 2);
    __half* w2hi = (__half*)alloc((size_t)DH * DH * 2);
    __half* w2lo = (__half*)alloc((size_t)DH * DH * 2);
    int*   deg   = (int*)alloc((size_t)N * 4);
    float* gsum  = (float*)alloc(64 * (size_t)DH * 4);   // adjacent to deg: one memset covers both
    float* dinv  = (float*)alloc((size_t)N * 4);
    int*   part  = (int*)alloc((size_t)N * 4);
    int*   bsum  = (int*)alloc(256 * 4);
    int*   rowptr= (int*)alloc((size_t)(N + 1) * 4);
    int*   cursor= (int*)alloc((size_t)N * 4);
    edge_t* edg  = (edge_t*)alloc((size_t)E * 8);

    hipMemsetAsync(deg, 0, (size_t)((char*)gsum - (char*)deg) + 64 * (size_t)DH * 4, stream);

    const int nb = (N + 255) / 256;
    const int wtot = DIN * DH + 2 * DH * DH;
    const int wb = (wtot + 255) / 256;
    const int degB = (E + 1023) / 1024;
    const int nx = N * DIN;
    const int xb = (nx + 1023) / 1024;

    k_degx  <<<degB + xb, 256, 0, stream>>>(dst, E, deg, degB, x, xh, nx);
    k_scan1w<<<nb + wb, 256, 0, stream>>>(deg, N, nb, part, bsum, dinv,
                                          W0, w0hi, w0lo, W1, w1hi, w1lo, W2, w2hi, w2lo, DIN, DH);
    k_scan3 <<<nb, 256, 0, stream>>>(part, bsum, nb, N, E, rowptr, cursor);
    k_fill  <<<(E + 255) / 256, 256, 0, stream>>>(src, dst, E, dinv, cursor, edg);

    const int gemmBlocks = (N + 127) / 128;

    // layer 0: agg(x fp16) -> fp16 A -> gemm(relu(.W0+b0)) -> fp16 H
    k_agg128<<<(N + 7) / 8, 256, 0, stream>>>(xh, rowptr, edg, dinv, ha, N);
    k_gemm_mfma<<<gemmBlocks, 512, 0, stream>>>(ha, w0hi, w0lo, b0, hbuf, N, DIN);
    // layer 1
    k_agg256<<<(N + 3) / 4, 256, 0, stream>>>(hbuf, rowptr, edg, dinv, ha, N);
    k_gemm_mfma<<<gemmBlocks, 512, 0, stream>>>(ha, w1hi, w1lo, b1, hbuf, N, DH);
    // layer 2 (fused pooling epilogue)
    k_agg256<<<(N + 3) / 4, 256, 0, stream>>>(hbuf, rowptr, edg, dinv, ha, N);
    k_gemm_pool<<<gemmBlocks, 512, 0, stream>>>(ha, w2hi, w2lo, b2, batch, gsum, N, DH);

    k_poolcls<<<64, 256, 0, stream>>>(gsum, batch, N, Wc1, bc1, Wc2, bc2, out);
}